// Round 4
// baseline (629.107 us; speedup 1.0000x reference)
//
#include <hip/hip_runtime.h>
#include <hip/hip_bf16.h>
#include <cstdint>
#include <cstddef>

#define NN 50000
#define EE 800000
#define FF 768
#define HH 256
#define GG 512
#define CC 2
#define NHIDD 128
#define ETOT (EE + NN)
#define NCHUNK 49   // ceil(NN/1024)

typedef __attribute__((ext_vector_type(8))) short bf16x8;   // 8 bf16 in 4 VGPRs
typedef __attribute__((ext_vector_type(4))) float f32x4;
typedef __attribute__((ext_vector_type(8))) unsigned short us8;

__device__ __forceinline__ float b2f(unsigned short u){
  union { float f; uint32_t i; } v; v.i = ((uint32_t)u) << 16; return v.f;
}
__device__ __forceinline__ unsigned short f2b(float f){
  uint32_t u = __float_as_uint(f);
  uint32_t r = (u + 0x7fffu + ((u >> 16) & 1u)) >> 16;
  return (unsigned short)r;
}
__device__ __forceinline__ float selu_f(float x){
  const float lam = 1.0507009873554805f, alp = 1.6732632423543772f;
  return x > 0.f ? lam * x : lam * alp * (__expf(x) - 1.f);
}

// direct-to-LDS 16B DMA (compiler never auto-emits this; bypasses VGPR round-trip AND regalloc load-sinking)
__device__ __forceinline__ void gload_lds16(const unsigned short* g, unsigned short* l){
  __builtin_amdgcn_global_load_lds((const __attribute__((address_space(1))) void*)g,
                                   (__attribute__((address_space(3))) void*)l, 16, 0, 0);
}

// ---------------- x fp32 -> bf16 (once; enables global_load_lds staging in gemm1) ----------------
__global__ __launch_bounds__(256) void xbf_kernel(const float* __restrict__ x, unsigned short* __restrict__ xb){
  size_t i = ((size_t)blockIdx.x * 256 + threadIdx.x) * 8;   // NN*FF = 38.4M, divisible by 8*256
  float4 f0 = *(const float4*)&x[i];
  float4 f1 = *(const float4*)&x[i + 4];
  us8 v;
  v[0] = f2b(f0.x); v[1] = f2b(f0.y); v[2] = f2b(f0.z); v[3] = f2b(f0.w);
  v[4] = f2b(f1.x); v[5] = f2b(f1.y); v[6] = f2b(f1.z); v[7] = f2b(f1.w);
  *(us8*)&xb[i] = v;
}

// ---------------- W swizzle + fp32->bf16: [K][256] f32 -> [K/32][256][32] bf16 ----------------
__global__ __launch_bounds__(256) void swizzleW(const float* __restrict__ W,
                                                unsigned short* __restrict__ Wsw, int K){
  int i = blockIdx.x * 256 + threadIdx.x;
  if (i < K * HH){
    int k = i / HH, n = i % HH;
    Wsw[(size_t)(k >> 5) * 8192 + n * 32 + (k & 31)] = f2b(W[i]);
  }
}

// ---------------- CSR build ----------------
__global__ __launch_bounds__(256) void zero_deg(int* deg){
  int i = blockIdx.x * 256 + threadIdx.x;
  if (i < NN) deg[i] = 0;
}

__global__ __launch_bounds__(256) void deg_kernel(const int* __restrict__ dstA, int* __restrict__ deg){
  int i = blockIdx.x * 256 + threadIdx.x;
  if (i < ETOT){
    int d = (i < EE) ? dstA[i] : (i - EE);   // self-loops appended
    atomicAdd(&deg[d], 1);
  }
}

__global__ __launch_bounds__(256) void scanA(const int* __restrict__ deg, int* __restrict__ bsum){
  __shared__ int red[256];
  int c = blockIdx.x, tid = threadIdx.x;
  int base = c * 1024 + tid * 4;
  int s = 0;
#pragma unroll
  for (int j = 0; j < 4; j++){ int idx = base + j; if (idx < NN) s += deg[idx]; }
  red[tid] = s; __syncthreads();
  for (int off = 128; off > 0; off >>= 1){
    if (tid < off) red[tid] += red[tid + off];
    __syncthreads();
  }
  if (tid == 0) bsum[c] = red[0];
}

__global__ void scanB(int* bsum){
  if (threadIdx.x == 0){
    int run = 0;
    for (int i = 0; i < NCHUNK; i++){ int v = bsum[i]; bsum[i] = run; run += v; }
  }
}

__global__ __launch_bounds__(256) void scanC(const int* __restrict__ deg, const int* __restrict__ bsum,
                                             int* __restrict__ row_ptr, int* __restrict__ fill_ptr){
  __shared__ int ts[256];
  int c = blockIdx.x, tid = threadIdx.x;
  int base = c * 1024 + tid * 4;
  int v[4]; int s = 0;
#pragma unroll
  for (int j = 0; j < 4; j++){ int idx = base + j; v[j] = (idx < NN) ? deg[idx] : 0; s += v[j]; }
  ts[tid] = s; __syncthreads();
  for (int off = 1; off < 256; off <<= 1){
    int add = (tid >= off) ? ts[tid - off] : 0;
    __syncthreads();
    ts[tid] += add;
    __syncthreads();
  }
  int run = ts[tid] - s + bsum[c];
#pragma unroll
  for (int j = 0; j < 4; j++){
    int idx = base + j;
    if (idx < NN){ row_ptr[idx] = run; fill_ptr[idx] = run; }
    run += v[j];
  }
  if (c == 0 && tid == 0) row_ptr[NN] = ETOT;
}

__global__ __launch_bounds__(256) void fill_kernel(const int* __restrict__ srcA, const int* __restrict__ dstA,
                                                   int* __restrict__ fill_ptr, int* __restrict__ csr_src){
  int i = blockIdx.x * 256 + threadIdx.x;
  if (i < ETOT){
    int s = (i < EE) ? srcA[i] : (i - EE);
    int d = (i < EE) ? dstA[i] : (i - EE);
    int pos = atomicAdd(&fill_ptr[d], 1);
    csr_src[pos] = s;
  }
}

// ---------------- MFMA GEMM v6: global_load_lds A staging (XOR-swizzled source), fused als/ald ----------------
// v5 post-mortem: compiler emitted 68 VGPRs regardless of launch_bounds allowance — regalloc sinks the
// staged loads, defeating every source-level pipeline. v6 stages A via __builtin_amdgcn_global_load_lds
// width=16 (HW DMA queue, zero VGPRs, no f2b in staging): LDS layout LINEAR (DMA requires it), bank
// conflicts handled by XOR-ing the 16B-chunk index with (row&7) on the per-lane GLOBAL source address
// (rule #21: same involution applied on ds_read). Epilogue computes als = h@a_s, ald = h@a_d from the
// fp32 accumulators (kills the alsald dispatch + a 25.6 MB h re-read per layer).
template<int K, int MINW>
__global__ __launch_bounds__(256, MINW) void gemm_mfma(const unsigned short* __restrict__ A,
                                                 const unsigned short* __restrict__ Wsw,
                                                 const float* __restrict__ a_s, const float* __restrict__ a_d,
                                                 unsigned short* __restrict__ out,
                                                 float* __restrict__ als, float* __restrict__ ald, int M){
  constexpr int CHROW = K / 8;                   // 16B chunks per row
  __shared__ unsigned short Al[32 * K];          // linear: K=768 -> 48 KB (3 blk/CU); K=256 -> 16 KB
  const int tid = threadIdx.x;
  const int m0 = blockIdx.x * 32;
  const int lane = tid & 63, w = tid >> 6;
  const int koff = (lane >> 4) * 8;              // k-offset (shorts) of this quad within a 32-k step
  const int arow = lane & 15;
  const int nrow = w * 64 + (lane & 15);         // B row (n)

  f32x4 acc[2][4];
#pragma unroll
  for (int rt = 0; rt < 2; rt++)
#pragma unroll
    for (int ct = 0; ct < 4; ct++) acc[rt][ct] = (f32x4){0.f, 0.f, 0.f, 0.f};

  // ---- A panel staging: 16B DMA per lane; LDS linear, source chunk XOR-swizzled ----
  constexpr int ROUNDS = (32 * CHROW) / 256;     // 12 (K=768) / 4 (K=256)
#pragma unroll
  for (int j = 0; j < ROUNDS; j++){
    int L16 = j * 256 + tid;                     // linear 16B-chunk index in panel
    int row = L16 / CHROW;
    int ch  = L16 - row * CHROW;
    int sch = ch ^ (row & 7);                    // inverse-swizzle the SOURCE (involution)
    int gr  = m0 + row; if (gr >= M) gr = M - 1; // clamp: garbage rows never stored (guards below)
    gload_lds16(A + (size_t)gr * K + sch * 8,
                &Al[(size_t)(j * 256 + w * 64) * 8]);   // wave-uniform dest; HW adds lane*16
  }

  // prefetch B[0] into regs while the DMA queue drains
  const unsigned short* bbase = Wsw + ((size_t)nrow * 32 + koff);
  bf16x8 bcur[2][4];
#pragma unroll
  for (int k2 = 0; k2 < 2; k2++)
#pragma unroll
    for (int ct = 0; ct < 4; ct++)
      bcur[k2][ct] = *(const bf16x8*)(bbase + (size_t)k2 * 8192 + ct * 512);  // 16 n-rows * 32

  __syncthreads();   // single vmcnt(0)+barrier: all DMA writes visible

  constexpr int NIT = K / 64;
  for (int ks = 0; ks < NIT; ks++){
    bf16x8 bnext[2][4];
    if (ks + 1 < NIT){
#pragma unroll
      for (int k2 = 0; k2 < 2; k2++)
#pragma unroll
        for (int ct = 0; ct < 4; ct++)
          bnext[k2][ct] = *(const bf16x8*)(bbase + (size_t)((ks + 1) * 2 + k2) * 8192 + ct * 512);
    }
    bf16x8 af[2][2];
#pragma unroll
    for (int k2 = 0; k2 < 2; k2++)
#pragma unroll
      for (int rt = 0; rt < 2; rt++){
        int R = rt * 16 + arow;
        int chb = (ks * 8 + k2 * 4 + (lane >> 4)) ^ (R & 7);   // read-side swizzle (same involution)
        af[k2][rt] = *(const bf16x8*)&Al[(size_t)R * K + chb * 8];
      }
#pragma unroll
    for (int k2 = 0; k2 < 2; k2++)
#pragma unroll
      for (int rt = 0; rt < 2; rt++)
#pragma unroll
        for (int ct = 0; ct < 4; ct++)
          acc[rt][ct] = __builtin_amdgcn_mfma_f32_16x16x32_bf16(af[k2][rt], bcur[k2][ct], acc[rt][ct], 0, 0, 0);
    if (ks + 1 < NIT){
#pragma unroll
      for (int k2 = 0; k2 < 2; k2++)
#pragma unroll
        for (int ct = 0; ct < 4; ct++) bcur[k2][ct] = bnext[k2][ct];
    }
  }

  // ---- C write (bf16 h) ----
#pragma unroll
  for (int rt = 0; rt < 2; rt++){
    int mbase = m0 + rt * 16 + (lane >> 4) * 4;
#pragma unroll
    for (int r = 0; r < 4; r++){
      int m = mbase + r;
      if (m < M){
        size_t ro = (size_t)m * HH + w * 64 + (lane & 15);
        out[ro + 0]  = f2b(acc[rt][0][r]);
        out[ro + 16] = f2b(acc[rt][1][r]);
        out[ro + 32] = f2b(acc[rt][2][r]);
        out[ro + 48] = f2b(acc[rt][3][r]);
      }
    }
  }

  // ---- fused als/ald: per-lane partials over its 4 cols, 16-lane shuffle reduce, cross-wave LDS reduce ----
  float as_c[4], ad_c[4];
#pragma unroll
  for (int ct = 0; ct < 4; ct++){
    int col = w * 64 + ct * 16 + (lane & 15);
    as_c[ct] = a_s[col]; ad_c[ct] = a_d[col];
  }
  float ps[2][4], pd[2][4];
#pragma unroll
  for (int rt = 0; rt < 2; rt++)
#pragma unroll
    for (int r = 0; r < 4; r++){
      float s = 0.f, d = 0.f;
#pragma unroll
      for (int ct = 0; ct < 4; ct++){ float v = acc[rt][ct][r]; s += v * as_c[ct]; d += v * ad_c[ct]; }
      ps[rt][r] = s; pd[rt][r] = d;
    }
#pragma unroll
  for (int off = 1; off < 16; off <<= 1){
#pragma unroll
    for (int rt = 0; rt < 2; rt++)
#pragma unroll
      for (int r = 0; r < 4; r++){
        ps[rt][r] += __shfl_xor(ps[rt][r], off);
        pd[rt][r] += __shfl_xor(pd[rt][r], off);
      }
  }
  __syncthreads();                       // all waves done reading Al -> safe to repurpose
  float* red = (float*)Al;               // [2][4 waves][32 rows] = 256 floats
  if ((lane & 15) == 0){
    int q = lane >> 4;
#pragma unroll
    for (int rt = 0; rt < 2; rt++)
#pragma unroll
      for (int r = 0; r < 4; r++){
        int row = rt * 16 + q * 4 + r;
        red[w * 32 + row]       = ps[rt][r];
        red[128 + w * 32 + row] = pd[rt][r];
      }
  }
  __syncthreads();
  if (tid < 32){
    float s = red[tid] + red[32 + tid] + red[64 + tid] + red[96 + tid];
    float d = red[128 + tid] + red[160 + tid] + red[192 + tid] + red[224 + tid];
    int m = m0 + tid;
    if (m < M){ als[m] = s; ald[m] = d; }
  }
}

// ---------------- wave-per-node fused softmax + aggregate + bias + SELU ----------------
__global__ __launch_bounds__(256) void agg_wave(const unsigned short* __restrict__ h,
    const float* __restrict__ als, const float* __restrict__ ald,
    const int* __restrict__ row_ptr, const int* __restrict__ csr_src,
    const float* __restrict__ bias, unsigned short* __restrict__ outp){
  int node = blockIdx.x * 4 + (threadIdx.x >> 6);
  int lane = threadIdx.x & 63;
  if (node >= NN) return;
  int base = row_ptr[node];
  int deg  = row_ptr[node + 1] - base;
  float aldd = ald[node];
  float den = 0.f;
  float a0 = 0.f, a1 = 0.f, a2 = 0.f, a3 = 0.f;
  const size_t fo = (size_t)lane * 4;
  for (int p0 = 0; p0 < deg; p0 += 64){
    int cnt = min(64, deg - p0);
    float ev = 0.f; int s = 0;
    if (lane < cnt){
      s = csr_src[base + p0 + lane];
      float v = als[s] + aldd;
      v = v > 0.f ? v : 0.2f * v;          // leaky_relu(0.2)
      ev = __expf(v);
    }
    den += ev;
    int j = 0;
    for (; j + 2 <= cnt; j += 2){
      float e0 = __shfl(ev, j), e1 = __shfl(ev, j + 1);
      int s0 = __shfl(s, j), s1 = __shfl(s, j + 1);
      ushort4 g0 = *(const ushort4*)&h[(size_t)s0 * HH + fo];
      ushort4 g1 = *(const ushort4*)&h[(size_t)s1 * HH + fo];
      a0 += e0 * b2f(g0.x) + e1 * b2f(g1.x);
      a1 += e0 * b2f(g0.y) + e1 * b2f(g1.y);
      a2 += e0 * b2f(g0.z) + e1 * b2f(g1.z);
      a3 += e0 * b2f(g0.w) + e1 * b2f(g1.w);
    }
    for (; j < cnt; j++){
      float e0 = __shfl(ev, j); int s0 = __shfl(s, j);
      ushort4 g0 = *(const ushort4*)&h[(size_t)s0 * HH + fo];
      a0 += e0 * b2f(g0.x); a1 += e0 * b2f(g0.y); a2 += e0 * b2f(g0.z); a3 += e0 * b2f(g0.w);
    }
  }
  for (int off = 32; off > 0; off >>= 1) den += __shfl_xor(den, off);
  float inv = 1.f / den;
  float4 b4 = *(const float4*)&bias[fo];
  ushort4 o;
  o.x = f2b(selu_f(a0 * inv + b4.x));
  o.y = f2b(selu_f(a1 * inv + b4.y));
  o.z = f2b(selu_f(a2 * inv + b4.z));
  o.w = f2b(selu_f(a3 * inv + b4.w));
  *(ushort4*)&outp[(size_t)node * HH + fo] = o;
}

// ---------------- tail ----------------
__global__ __launch_bounds__(256) void first_kernel(const int* __restrict__ batch, int* __restrict__ first_idx){
  int n = blockIdx.x * 256 + threadIdx.x;
  if (n < NN){
    int b = batch[n];
    if (n == 0 || batch[n - 1] != b) first_idx[b] = n;
  }
  if (blockIdx.x == 0 && threadIdx.x == 0) first_idx[GG] = NN;
}

__global__ __launch_bounds__(256) void pool_kernel(const unsigned short* __restrict__ x3,
    const int* __restrict__ first_idx, float* __restrict__ pooled){
  int g = blockIdx.x, f = threadIdx.x;
  int s = first_idx[g], e = first_idx[g + 1];
  float acc = 0.f;
  for (int n = s; n < e; n++) acc += b2f(x3[(size_t)n * HH + f]);
  pooled[g * HH + f] = selu_f(acc / (float)(e - s));
}

__global__ __launch_bounds__(128) void z1_kernel(const float* __restrict__ pooled,
    const float* __restrict__ Wf1, const float* __restrict__ bf1,
    float* __restrict__ z1){
  __shared__ float pr[HH];
  int g = blockIdx.x, t = threadIdx.x;
  pr[t] = pooled[g * HH + t];
  pr[t + 128] = pooled[g * HH + t + 128];
  __syncthreads();
  float acc = 0.f;
  for (int k = 0; k < HH; k++) acc += pr[k] * Wf1[k * NHIDD + t];
  z1[g * NHIDD + t] = selu_f(acc + bf1[t]);
}

__global__ __launch_bounds__(128) void news_kernel(const float* __restrict__ x,
    const int* __restrict__ first_idx, const float* __restrict__ W0,
    const float* __restrict__ b0, float* __restrict__ znews){
  __shared__ float xr[FF];
  int g = blockIdx.x, t = threadIdx.x;
  int root = first_idx[g];
  for (int k = t; k < FF; k += 128) xr[k] = x[(size_t)root * FF + k];
  __syncthreads();
  float acc = 0.f;
  for (int k = 0; k < FF; k++) acc += xr[k] * W0[k * NHIDD + t];
  acc += b0[t];
  znews[g * NHIDD + t] = acc > 0.f ? acc : 0.f;
}

// ---------------- final: concat -> fc1(relu) -> fc2 -> log_softmax; OUTPUT FLOAT32 ----------------
__global__ __launch_bounds__(128) void final_kernel(const float* __restrict__ z1,
    const float* __restrict__ znews, const float* __restrict__ Wf1,
    const float* __restrict__ bf1, const float* __restrict__ Wf2,
    const float* __restrict__ bf2, float* __restrict__ out){
  __shared__ float zc[HH];
  __shared__ float l0s[2], l1s[2];
  int g = blockIdx.x, t = threadIdx.x;
  zc[t] = z1[g * NHIDD + t];
  zc[NHIDD + t] = znews[g * NHIDD + t];
  __syncthreads();
  float acc = 0.f;
  for (int k = 0; k < HH; k++) acc += zc[k] * Wf1[k * NHIDD + t];
  float z2 = acc + bf1[t]; z2 = z2 > 0.f ? z2 : 0.f;
  float p0 = z2 * Wf2[t * CC + 0];
  float p1 = z2 * Wf2[t * CC + 1];
  for (int off = 32; off > 0; off >>= 1){ p0 += __shfl_xor(p0, off); p1 += __shfl_xor(p1, off); }
  int lane = t & 63, wid = t >> 6;
  if (lane == 0){ l0s[wid] = p0; l1s[wid] = p1; }
  __syncthreads();
  if (t == 0){
    float l0 = l0s[0] + l0s[1] + bf2[0];
    float l1 = l1s[0] + l1s[1] + bf2[1];
    float mx = fmaxf(l0, l1);
    float lse = mx + logf(__expf(l0 - mx) + __expf(l1 - mx));
    out[g * CC + 0] = l0 - lse;
    out[g * CC + 1] = l1 - lse;
  }
}

extern "C" void kernel_launch(void* const* d_in, const int* in_sizes, int n_in,
                              void* d_out, int out_size, void* d_ws, size_t ws_size,
                              hipStream_t stream){
  const float* x          = (const float*)d_in[0];
  const int* edge_index   = (const int*)d_in[1];
  const int* batch        = (const int*)d_in[2];
  const float* W1  = (const float*)d_in[3];
  const float* as1 = (const float*)d_in[4];
  const float* ad1 = (const float*)d_in[5];
  const float* b1  = (const float*)d_in[6];
  const float* W2  = (const float*)d_in[7];
  const float* as2 = (const float*)d_in[8];
  const float* ad2 = (const float*)d_in[9];
  const float* b2  = (const float*)d_in[10];
  const float* W0  = (const float*)d_in[11];
  const float* b0  = (const float*)d_in[12];
  const float* Wf1 = (const float*)d_in[13];
  const float* bf1 = (const float*)d_in[14];
  const float* Wf2 = (const float*)d_in[15];
  const float* bf2 = (const float*)d_in[16];
  float* out = (float*)d_out;

  char* w = (char*)d_ws;
  size_t off = 0;
  auto alloc = [&](size_t bytes){ size_t o = off; off += (bytes + 255) & ~(size_t)255; return o; };
  unsigned short* h    = (unsigned short*)(w + alloc((size_t)NN * HH * 2));   // 25.6 MB
  unsigned short* x2   = (unsigned short*)(w + alloc((size_t)NN * HH * 2));   // 25.6 MB
  unsigned short* xb   = (unsigned short*)(w + alloc((size_t)NN * FF * 2));   // 76.8 MB (x in bf16)
  unsigned short* Wsw1 = (unsigned short*)(w + alloc((size_t)FF * HH * 2));
  unsigned short* Wsw2 = (unsigned short*)(w + alloc((size_t)HH * HH * 2));
  float* als     = (float*)(w + alloc((size_t)NN * 4));
  float* ald     = (float*)(w + alloc((size_t)NN * 4));
  int*   deg     = (int*)(w + alloc((size_t)NN * 4));
  int*   row_ptr = (int*)(w + alloc((size_t)(NN + 1) * 4));
  int*   fillp   = (int*)(w + alloc((size_t)NN * 4));
  int*   csr_src = (int*)(w + alloc((size_t)ETOT * 4));
  int*   bsum    = (int*)(w + alloc(64 * 4));
  int*   firsti  = (int*)(w + alloc((size_t)(GG + 1) * 4));
  float* pooled  = (float*)(w + alloc((size_t)GG * HH * 4));
  float* z1      = (float*)(w + alloc((size_t)GG * NHIDD * 4));
  float* znews   = (float*)(w + alloc((size_t)GG * NHIDD * 4));

  const int* srcA = edge_index;
  const int* dstA = edge_index + EE;

  // weight swizzle (fp32 -> bf16, MFMA order) + x -> bf16
  swizzleW<<<(FF * HH + 255) / 256, 256, 0, stream>>>(W1, Wsw1, FF);
  swizzleW<<<(HH * HH + 255) / 256, 256, 0, stream>>>(W2, Wsw2, HH);
  xbf_kernel<<<(NN * FF) / (256 * 8), 256, 0, stream>>>(x, xb);

  // CSR build (shared by both GAT layers)
  zero_deg<<<(NN + 255) / 256, 256, 0, stream>>>(deg);
  deg_kernel<<<(ETOT + 255) / 256, 256, 0, stream>>>(dstA, deg);
  scanA<<<NCHUNK, 256, 0, stream>>>(deg, bsum);
  scanB<<<1, 64, 0, stream>>>(bsum);
  scanC<<<NCHUNK, 256, 0, stream>>>(deg, bsum, row_ptr, fillp);
  fill_kernel<<<(ETOT + 255) / 256, 256, 0, stream>>>(srcA, dstA, fillp, csr_src);

  const int gemm_grid = (NN + 31) / 32;   // 32-row full-K panels -> 1563 blocks
  // GAT layer 1 (A = bf16 xb via DMA staging; als/ald fused into epilogue)
  gemm_mfma<FF, 3><<<gemm_grid, 256, 0, stream>>>(xb, Wsw1, as1, ad1, h, als, ald, NN);
  agg_wave<<<(NN + 3) / 4, 256, 0, stream>>>(h, als, ald, row_ptr, csr_src, b1, x2);
  // GAT layer 2 (A = bf16 x2)
  gemm_mfma<HH, 3><<<gemm_grid, 256, 0, stream>>>(x2, Wsw2, as2, ad2, h, als, ald, NN);
  agg_wave<<<(NN + 3) / 4, 256, 0, stream>>>(h, als, ald, row_ptr, csr_src, b2, x2);
  // head
  first_kernel<<<(NN + 255) / 256, 256, 0, stream>>>(batch, firsti);
  pool_kernel<<<GG, 256, 0, stream>>>(x2, firsti, pooled);
  z1_kernel<<<GG, 128, 0, stream>>>(pooled, Wf1, bf1, z1);
  news_kernel<<<GG, 128, 0, stream>>>(x, firsti, W0, b0, znews);
  final_kernel<<<GG, 128, 0, stream>>>(z1, znews, Wf1, bf1, Wf2, bf2, out);
}

// Round 5
// 617.980 us; speedup vs baseline: 1.0180x; 1.0180x over previous
//
#include <hip/hip_runtime.h>
#include <hip/hip_bf16.h>
#include <cstdint>
#include <cstddef>

#define NN 50000
#define EE 800000
#define FF 768
#define HH 256
#define GG 512
#define CC 2
#define NHIDD 128
#define ETOT (EE + NN)
#define NCHUNK 49   // ceil(NN/1024)

typedef __attribute__((ext_vector_type(8))) short bf16x8;   // 8 bf16 in 4 VGPRs
typedef __attribute__((ext_vector_type(4))) float f32x4;
typedef __attribute__((ext_vector_type(8))) unsigned short us8;

__device__ __forceinline__ float b2f(unsigned short u){
  union { float f; uint32_t i; } v; v.i = ((uint32_t)u) << 16; return v.f;
}
__device__ __forceinline__ unsigned short f2b(float f){
  uint32_t u = __float_as_uint(f);
  uint32_t r = (u + 0x7fffu + ((u >> 16) & 1u)) >> 16;
  return (unsigned short)r;
}
__device__ __forceinline__ float selu_f(float x){
  const float lam = 1.0507009873554805f, alp = 1.6732632423543772f;
  return x > 0.f ? lam * x : lam * alp * (__expf(x) - 1.f);
}

// direct-to-LDS 16B DMA (compiler never auto-emits this; bypasses VGPR round-trip AND regalloc load-sinking)
__device__ __forceinline__ void gload_lds16(const unsigned short* g, unsigned short* l){
  __builtin_amdgcn_global_load_lds((const __attribute__((address_space(1))) void*)g,
                                   (__attribute__((address_space(3))) void*)l, 16, 0, 0);
}

// ---------------- x fp32 -> bf16 (once; enables global_load_lds staging in gemm1) ----------------
__global__ __launch_bounds__(256) void xbf_kernel(const float* __restrict__ x, unsigned short* __restrict__ xb){
  size_t i = ((size_t)blockIdx.x * 256 + threadIdx.x) * 8;   // NN*FF = 38.4M, divisible by 8*256
  float4 f0 = *(const float4*)&x[i];
  float4 f1 = *(const float4*)&x[i + 4];
  us8 v;
  v[0] = f2b(f0.x); v[1] = f2b(f0.y); v[2] = f2b(f0.z); v[3] = f2b(f0.w);
  v[4] = f2b(f1.x); v[5] = f2b(f1.y); v[6] = f2b(f1.z); v[7] = f2b(f1.w);
  *(us8*)&xb[i] = v;
}

// ---------------- W swizzle + fp32->bf16: [K][256] f32 -> [K/32][256][32] bf16 ----------------
__global__ __launch_bounds__(256) void swizzleW(const float* __restrict__ W,
                                                unsigned short* __restrict__ Wsw, int K){
  int i = blockIdx.x * 256 + threadIdx.x;
  if (i < K * HH){
    int k = i / HH, n = i % HH;
    Wsw[(size_t)(k >> 5) * 8192 + n * 32 + (k & 31)] = f2b(W[i]);
  }
}

// ---------------- CSR build ----------------
__global__ __launch_bounds__(256) void zero_deg(int* deg){
  int i = blockIdx.x * 256 + threadIdx.x;
  if (i < NN) deg[i] = 0;
}

__global__ __launch_bounds__(256) void deg_kernel(const int* __restrict__ dstA, int* __restrict__ deg){
  int i = blockIdx.x * 256 + threadIdx.x;
  if (i < ETOT){
    int d = (i < EE) ? dstA[i] : (i - EE);   // self-loops appended
    atomicAdd(&deg[d], 1);
  }
}

__global__ __launch_bounds__(256) void scanA(const int* __restrict__ deg, int* __restrict__ bsum){
  __shared__ int red[256];
  int c = blockIdx.x, tid = threadIdx.x;
  int base = c * 1024 + tid * 4;
  int s = 0;
#pragma unroll
  for (int j = 0; j < 4; j++){ int idx = base + j; if (idx < NN) s += deg[idx]; }
  red[tid] = s; __syncthreads();
  for (int off = 128; off > 0; off >>= 1){
    if (tid < off) red[tid] += red[tid + off];
    __syncthreads();
  }
  if (tid == 0) bsum[c] = red[0];
}

// scanB folded in: chunk base computed by an in-block reduce of bsum[0..c)
__global__ __launch_bounds__(256) void scanC(const int* __restrict__ deg, const int* __restrict__ bsum,
                                             int* __restrict__ row_ptr, int* __restrict__ fill_ptr){
  __shared__ int ts[256];
  __shared__ int cbase;
  int c = blockIdx.x, tid = threadIdx.x;
  int pb = (tid < c) ? bsum[tid] : 0;    // NCHUNK=49 <= 256
  ts[tid] = pb; __syncthreads();
  for (int off = 128; off > 0; off >>= 1){
    if (tid < off) ts[tid] += ts[tid + off];
    __syncthreads();
  }
  if (tid == 0) cbase = ts[0];
  __syncthreads();
  int base = c * 1024 + tid * 4;
  int v[4]; int s = 0;
#pragma unroll
  for (int j = 0; j < 4; j++){ int idx = base + j; v[j] = (idx < NN) ? deg[idx] : 0; s += v[j]; }
  ts[tid] = s; __syncthreads();
  for (int off = 1; off < 256; off <<= 1){
    int add = (tid >= off) ? ts[tid - off] : 0;
    __syncthreads();
    ts[tid] += add;
    __syncthreads();
  }
  int run = ts[tid] - s + cbase;
#pragma unroll
  for (int j = 0; j < 4; j++){
    int idx = base + j;
    if (idx < NN){ row_ptr[idx] = run; fill_ptr[idx] = run; }
    run += v[j];
  }
  if (c == 0 && tid == 0) row_ptr[NN] = ETOT;
}

__global__ __launch_bounds__(256) void fill_kernel(const int* __restrict__ srcA, const int* __restrict__ dstA,
                                                   int* __restrict__ fill_ptr, int* __restrict__ csr_src){
  int i = blockIdx.x * 256 + threadIdx.x;
  if (i < ETOT){
    int s = (i < EE) ? srcA[i] : (i - EE);
    int d = (i < EE) ? dstA[i] : (i - EE);
    int pos = atomicAdd(&fill_ptr[d], 1);
    csr_src[pos] = s;
  }
}

// ---------------- MFMA GEMM v6 (frozen from round 4): global_load_lds A staging, fused als/ald ----------------
template<int K, int MINW>
__global__ __launch_bounds__(256, MINW) void gemm_mfma(const unsigned short* __restrict__ A,
                                                 const unsigned short* __restrict__ Wsw,
                                                 const float* __restrict__ a_s, const float* __restrict__ a_d,
                                                 unsigned short* __restrict__ out,
                                                 float* __restrict__ als, float* __restrict__ ald, int M){
  constexpr int CHROW = K / 8;                   // 16B chunks per row
  __shared__ unsigned short Al[32 * K];          // linear: K=768 -> 48 KB (3 blk/CU); K=256 -> 16 KB
  const int tid = threadIdx.x;
  const int m0 = blockIdx.x * 32;
  const int lane = tid & 63, w = tid >> 6;
  const int koff = (lane >> 4) * 8;              // k-offset (shorts) of this quad within a 32-k step
  const int arow = lane & 15;
  const int nrow = w * 64 + (lane & 15);         // B row (n)

  f32x4 acc[2][4];
#pragma unroll
  for (int rt = 0; rt < 2; rt++)
#pragma unroll
    for (int ct = 0; ct < 4; ct++) acc[rt][ct] = (f32x4){0.f, 0.f, 0.f, 0.f};

  // ---- A panel staging: 16B DMA per lane; LDS linear, source chunk XOR-swizzled ----
  constexpr int ROUNDS = (32 * CHROW) / 256;     // 12 (K=768) / 4 (K=256)
#pragma unroll
  for (int j = 0; j < ROUNDS; j++){
    int L16 = j * 256 + tid;                     // linear 16B-chunk index in panel
    int row = L16 / CHROW;
    int ch  = L16 - row * CHROW;
    int sch = ch ^ (row & 7);                    // inverse-swizzle the SOURCE (involution)
    int gr  = m0 + row; if (gr >= M) gr = M - 1; // clamp: garbage rows never stored (guards below)
    gload_lds16(A + (size_t)gr * K + sch * 8,
                &Al[(size_t)(j * 256 + w * 64) * 8]);   // wave-uniform dest; HW adds lane*16
  }

  // prefetch B[0] into regs while the DMA queue drains
  const unsigned short* bbase = Wsw + ((size_t)nrow * 32 + koff);
  bf16x8 bcur[2][4];
#pragma unroll
  for (int k2 = 0; k2 < 2; k2++)
#pragma unroll
    for (int ct = 0; ct < 4; ct++)
      bcur[k2][ct] = *(const bf16x8*)(bbase + (size_t)k2 * 8192 + ct * 512);  // 16 n-rows * 32

  __syncthreads();   // single vmcnt(0)+barrier: all DMA writes visible

  constexpr int NIT = K / 64;
  for (int ks = 0; ks < NIT; ks++){
    bf16x8 bnext[2][4];
    if (ks + 1 < NIT){
#pragma unroll
      for (int k2 = 0; k2 < 2; k2++)
#pragma unroll
        for (int ct = 0; ct < 4; ct++)
          bnext[k2][ct] = *(const bf16x8*)(bbase + (size_t)((ks + 1) * 2 + k2) * 8192 + ct * 512);
    }
    bf16x8 af[2][2];
#pragma unroll
    for (int k2 = 0; k2 < 2; k2++)
#pragma unroll
      for (int rt = 0; rt < 2; rt++){
        int R = rt * 16 + arow;
        int chb = (ks * 8 + k2 * 4 + (lane >> 4)) ^ (R & 7);   // read-side swizzle (same involution)
        af[k2][rt] = *(const bf16x8*)&Al[(size_t)R * K + chb * 8];
      }
#pragma unroll
    for (int k2 = 0; k2 < 2; k2++)
#pragma unroll
      for (int rt = 0; rt < 2; rt++)
#pragma unroll
        for (int ct = 0; ct < 4; ct++)
          acc[rt][ct] = __builtin_amdgcn_mfma_f32_16x16x32_bf16(af[k2][rt], bcur[k2][ct], acc[rt][ct], 0, 0, 0);
    if (ks + 1 < NIT){
#pragma unroll
      for (int k2 = 0; k2 < 2; k2++)
#pragma unroll
        for (int ct = 0; ct < 4; ct++) bcur[k2][ct] = bnext[k2][ct];
    }
  }

  // ---- C write (bf16 h) ----
#pragma unroll
  for (int rt = 0; rt < 2; rt++){
    int mbase = m0 + rt * 16 + (lane >> 4) * 4;
#pragma unroll
    for (int r = 0; r < 4; r++){
      int m = mbase + r;
      if (m < M){
        size_t ro = (size_t)m * HH + w * 64 + (lane & 15);
        out[ro + 0]  = f2b(acc[rt][0][r]);
        out[ro + 16] = f2b(acc[rt][1][r]);
        out[ro + 32] = f2b(acc[rt][2][r]);
        out[ro + 48] = f2b(acc[rt][3][r]);
      }
    }
  }

  // ---- fused als/ald from fp32 accumulators ----
  float as_c[4], ad_c[4];
#pragma unroll
  for (int ct = 0; ct < 4; ct++){
    int col = w * 64 + ct * 16 + (lane & 15);
    as_c[ct] = a_s[col]; ad_c[ct] = a_d[col];
  }
  float ps[2][4], pd[2][4];
#pragma unroll
  for (int rt = 0; rt < 2; rt++)
#pragma unroll
    for (int r = 0; r < 4; r++){
      float s = 0.f, d = 0.f;
#pragma unroll
      for (int ct = 0; ct < 4; ct++){ float v = acc[rt][ct][r]; s += v * as_c[ct]; d += v * ad_c[ct]; }
      ps[rt][r] = s; pd[rt][r] = d;
    }
#pragma unroll
  for (int off = 1; off < 16; off <<= 1){
#pragma unroll
    for (int rt = 0; rt < 2; rt++)
#pragma unroll
      for (int r = 0; r < 4; r++){
        ps[rt][r] += __shfl_xor(ps[rt][r], off);
        pd[rt][r] += __shfl_xor(pd[rt][r], off);
      }
  }
  __syncthreads();                       // all waves done reading Al -> safe to repurpose
  float* red = (float*)Al;               // [2][4 waves][32 rows] = 256 floats
  if ((lane & 15) == 0){
    int q = lane >> 4;
#pragma unroll
    for (int rt = 0; rt < 2; rt++)
#pragma unroll
      for (int r = 0; r < 4; r++){
        int row = rt * 16 + q * 4 + r;
        red[w * 32 + row]       = ps[rt][r];
        red[128 + w * 32 + row] = pd[rt][r];
      }
  }
  __syncthreads();
  if (tid < 32){
    float s = red[tid] + red[32 + tid] + red[64 + tid] + red[96 + tid];
    float d = red[128 + tid] + red[160 + tid] + red[192 + tid] + red[224 + tid];
    int m = m0 + tid;
    if (m < M){ als[m] = s; ald[m] = d; }
  }
}

// ---------------- agg v2: softmax + aggregate; 8 feats/lane, 2 edges per 16B load, 2 loads in flight ----
// Theory: the old loop issued 2x 8B loads + 4 shuffles per 2 edges with ~1 load in flight -> latency/issue
// bound. Now lanes 0-31 process even edges, lanes 32-63 odd edges; each lane covers 8 features (ushort8,
// full dwordx4 load). Main loop does 4 edges/step with both loads issued before use. Halves merged with
// one shfl_xor(32) per accumulator at the end.
__global__ __launch_bounds__(256) void agg_wave(const unsigned short* __restrict__ h,
    const float* __restrict__ als, const float* __restrict__ ald,
    const int* __restrict__ row_ptr, const int* __restrict__ csr_src,
    const float* __restrict__ bias, unsigned short* __restrict__ outp){
  int node = blockIdx.x * 4 + (threadIdx.x >> 6);
  int lane = threadIdx.x & 63;
  if (node >= NN) return;
  int base = row_ptr[node];
  int deg  = row_ptr[node + 1] - base;
  float aldd = ald[node];
  float den = 0.f;
  float a[8] = {0.f, 0.f, 0.f, 0.f, 0.f, 0.f, 0.f, 0.f};
  const int f8 = (lane & 31) * 8;        // this lane's 8-feature slice
  const int half = lane >> 5;            // 0: even edges, 1: odd edges
  for (int p0 = 0; p0 < deg; p0 += 64){
    int cnt = min(64, deg - p0);         // wave-uniform
    float ev = 0.f; int s = 0;
    if (lane < cnt){
      s = csr_src[base + p0 + lane];
      float v = als[s] + aldd;
      v = v > 0.f ? v : 0.2f * v;        // leaky_relu(0.2)
      ev = __expf(v);
    }
    den += ev;
    int j = 0;
    for (; j + 4 <= cnt; j += 4){        // 4 edges per step, 2 independent loads
      int j0 = j + half, j1 = j + 2 + half;
      int s0 = __shfl(s, j0), s1 = __shfl(s, j1);
      float e0 = __shfl(ev, j0), e1 = __shfl(ev, j1);
      us8 g0 = *(const us8*)&h[(size_t)s0 * HH + f8];
      us8 g1 = *(const us8*)&h[(size_t)s1 * HH + f8];
#pragma unroll
      for (int i = 0; i < 8; i++) a[i] += e0 * b2f(g0[i]) + e1 * b2f(g1[i]);
    }
    for (; j < cnt; j += 2){             // 0-3 remaining edges
      int jj = j + half;
      int sj = __shfl(s, jj & 63);       // lanes >= cnt hold s=0 -> safe address
      float ejr = __shfl(ev, jj & 63);
      float ej = (jj < cnt) ? ejr : 0.f;
      us8 gj = *(const us8*)&h[(size_t)sj * HH + f8];
#pragma unroll
      for (int i = 0; i < 8; i++) a[i] += ej * b2f(gj[i]);
    }
  }
  for (int off = 32; off > 0; off >>= 1) den += __shfl_xor(den, off);
#pragma unroll
  for (int i = 0; i < 8; i++) a[i] += __shfl_xor(a[i], 32);   // merge even/odd halves
  if (lane < 32){
    float inv = 1.f / den;
    float4 b4a = *(const float4*)&bias[f8];
    float4 b4b = *(const float4*)&bias[f8 + 4];
    us8 o;
    o[0] = f2b(selu_f(a[0] * inv + b4a.x));
    o[1] = f2b(selu_f(a[1] * inv + b4a.y));
    o[2] = f2b(selu_f(a[2] * inv + b4a.z));
    o[3] = f2b(selu_f(a[3] * inv + b4a.w));
    o[4] = f2b(selu_f(a[4] * inv + b4b.x));
    o[5] = f2b(selu_f(a[5] * inv + b4b.y));
    o[6] = f2b(selu_f(a[6] * inv + b4b.z));
    o[7] = f2b(selu_f(a[7] * inv + b4b.w));
    *(us8*)&outp[(size_t)node * HH + f8] = o;
  }
}

// ---------------- fused head: pool + z1 + news + final per graph (binary-searched bounds) ----------------
__global__ __launch_bounds__(256) void head_kernel(const unsigned short* __restrict__ x3,
    const int* __restrict__ batch, const float* __restrict__ x,
    const float* __restrict__ W0, const float* __restrict__ b0,
    const float* __restrict__ Wf1, const float* __restrict__ bf1,
    const float* __restrict__ Wf2, const float* __restrict__ bf2,
    float* __restrict__ out){
  __shared__ float pr[HH];      // pooled (selu applied)
  __shared__ float xr[FF];      // root-node features
  __shared__ float zc[HH];      // concat [z1, news]
  __shared__ int se[2];
  __shared__ float l0s[2], l1s[2];
  int g = blockIdx.x, t = threadIdx.x;
  if (t < 2){                   // graph bounds: first n with batch[n] >= g (+t)
    int target = g + t, lo = 0, hi = NN;
    while (lo < hi){ int mid = (lo + hi) >> 1; if (batch[mid] < target) lo = mid + 1; else hi = mid; }
    se[t] = lo;
  }
  __syncthreads();
  int s = se[0], e = se[1];
  {                             // global mean pool over the graph, feature t
    float acc = 0.f;
    for (int n = s; n < e; n++) acc += b2f(x3[(size_t)n * HH + t]);
    pr[t] = selu_f(acc / (float)(e - s));
  }
  for (int k = t; k < FF; k += 256) xr[k] = x[(size_t)s * FF + k];   // root = first node
  __syncthreads();
  if (t < NHIDD){               // waves 0-1: z1 = selu(pr @ Wf1 + bf1)
    float acc = 0.f;
    for (int k = 0; k < HH; k++) acc += pr[k] * Wf1[k * NHIDD + t];
    zc[t] = selu_f(acc + bf1[t]);
  } else {                      // waves 2-3: news = relu(x_root @ W0 + b0)
    int t2 = t - NHIDD;
    float acc = 0.f;
    for (int k = 0; k < FF; k++) acc += xr[k] * W0[k * NHIDD + t2];
    acc += b0[t2];
    zc[NHIDD + t2] = acc > 0.f ? acc : 0.f;
  }
  __syncthreads();
  if (t < NHIDD){               // z2 = relu(zc @ Wf1 + bf1); logits; 2-wave reduce
    float acc = 0.f;
    for (int k = 0; k < HH; k++) acc += zc[k] * Wf1[k * NHIDD + t];
    float z2 = acc + bf1[t]; z2 = z2 > 0.f ? z2 : 0.f;
    float p0 = z2 * Wf2[t * CC + 0];
    float p1 = z2 * Wf2[t * CC + 1];
    for (int off = 32; off > 0; off >>= 1){ p0 += __shfl_xor(p0, off); p1 += __shfl_xor(p1, off); }
    if ((t & 63) == 0){ l0s[t >> 6] = p0; l1s[t >> 6] = p1; }
  }
  __syncthreads();
  if (t == 0){
    float l0 = l0s[0] + l0s[1] + bf2[0];
    float l1 = l1s[0] + l1s[1] + bf2[1];
    float mx = fmaxf(l0, l1);
    float lse = mx + logf(__expf(l0 - mx) + __expf(l1 - mx));
    out[g * CC + 0] = l0 - lse;
    out[g * CC + 1] = l1 - lse;
  }
}

extern "C" void kernel_launch(void* const* d_in, const int* in_sizes, int n_in,
                              void* d_out, int out_size, void* d_ws, size_t ws_size,
                              hipStream_t stream){
  const float* x          = (const float*)d_in[0];
  const int* edge_index   = (const int*)d_in[1];
  const int* batch        = (const int*)d_in[2];
  const float* W1  = (const float*)d_in[3];
  const float* as1 = (const float*)d_in[4];
  const float* ad1 = (const float*)d_in[5];
  const float* b1  = (const float*)d_in[6];
  const float* W2  = (const float*)d_in[7];
  const float* as2 = (const float*)d_in[8];
  const float* ad2 = (const float*)d_in[9];
  const float* b2  = (const float*)d_in[10];
  const float* W0  = (const float*)d_in[11];
  const float* b0  = (const float*)d_in[12];
  const float* Wf1 = (const float*)d_in[13];
  const float* bf1 = (const float*)d_in[14];
  const float* Wf2 = (const float*)d_in[15];
  const float* bf2 = (const float*)d_in[16];
  float* out = (float*)d_out;

  char* w = (char*)d_ws;
  size_t off = 0;
  auto alloc = [&](size_t bytes){ size_t o = off; off += (bytes + 255) & ~(size_t)255; return o; };
  unsigned short* h    = (unsigned short*)(w + alloc((size_t)NN * HH * 2));   // 25.6 MB
  unsigned short* x2   = (unsigned short*)(w + alloc((size_t)NN * HH * 2));   // 25.6 MB
  unsigned short* xb   = (unsigned short*)(w + alloc((size_t)NN * FF * 2));   // 76.8 MB (x in bf16)
  unsigned short* Wsw1 = (unsigned short*)(w + alloc((size_t)FF * HH * 2));
  unsigned short* Wsw2 = (unsigned short*)(w + alloc((size_t)HH * HH * 2));
  float* als     = (float*)(w + alloc((size_t)NN * 4));
  float* ald     = (float*)(w + alloc((size_t)NN * 4));
  int*   deg     = (int*)(w + alloc((size_t)NN * 4));
  int*   row_ptr = (int*)(w + alloc((size_t)(NN + 1) * 4));
  int*   fillp   = (int*)(w + alloc((size_t)NN * 4));
  int*   csr_src = (int*)(w + alloc((size_t)ETOT * 4));
  int*   bsum    = (int*)(w + alloc(64 * 4));

  const int* srcA = edge_index;
  const int* dstA = edge_index + EE;

  // weight swizzle (fp32 -> bf16, MFMA order) + x -> bf16
  swizzleW<<<(FF * HH + 255) / 256, 256, 0, stream>>>(W1, Wsw1, FF);
  swizzleW<<<(HH * HH + 255) / 256, 256, 0, stream>>>(W2, Wsw2, HH);
  xbf_kernel<<<(NN * FF) / (256 * 8), 256, 0, stream>>>(x, xb);

  // CSR build (shared by both GAT layers)
  zero_deg<<<(NN + 255) / 256, 256, 0, stream>>>(deg);
  deg_kernel<<<(ETOT + 255) / 256, 256, 0, stream>>>(dstA, deg);
  scanA<<<NCHUNK, 256, 0, stream>>>(deg, bsum);
  scanC<<<NCHUNK, 256, 0, stream>>>(deg, bsum, row_ptr, fillp);
  fill_kernel<<<(ETOT + 255) / 256, 256, 0, stream>>>(srcA, dstA, fillp, csr_src);

  const int gemm_grid = (NN + 31) / 32;   // 32-row full-K panels -> 1563 blocks
  // GAT layer 1 (A = bf16 xb via DMA staging; als/ald fused into epilogue)
  gemm_mfma<FF, 3><<<gemm_grid, 256, 0, stream>>>(xb, Wsw1, as1, ad1, h, als, ald, NN);
  agg_wave<<<(NN + 3) / 4, 256, 0, stream>>>(h, als, ald, row_ptr, csr_src, b1, x2);
  // GAT layer 2 (A = bf16 x2)
  gemm_mfma<HH, 3><<<gemm_grid, 256, 0, stream>>>(x2, Wsw2, as2, ad2, h, als, ald, NN);
  agg_wave<<<(NN + 3) / 4, 256, 0, stream>>>(h, als, ald, row_ptr, csr_src, b2, x2);
  // fused head (pool + z1 + news + final; bounds via binary search)
  head_kernel<<<GG, 256, 0, stream>>>(x2, batch, x, W0, b0, Wf1, bf1, Wf2, bf2, out);
}

// Round 6
// 580.511 us; speedup vs baseline: 1.0837x; 1.0645x over previous
//
#include <hip/hip_runtime.h>
#include <hip/hip_bf16.h>
#include <cstdint>
#include <cstddef>

#define NN 50000
#define EE 800000
#define FF 768
#define HH 256
#define GG 512
#define CC 2
#define NHIDD 128
#define ETOT (EE + NN)
#define NCHUNK 49   // ceil(NN/1024)

typedef __attribute__((ext_vector_type(8))) short bf16x8;   // 8 bf16 in 4 VGPRs
typedef __attribute__((ext_vector_type(4))) float f32x4;
typedef __attribute__((ext_vector_type(8))) unsigned short us8;

__device__ __forceinline__ float b2f(unsigned short u){
  union { float f; uint32_t i; } v; v.i = ((uint32_t)u) << 16; return v.f;
}
__device__ __forceinline__ unsigned short f2b(float f){
  uint32_t u = __float_as_uint(f);
  uint32_t r = (u + 0x7fffu + ((u >> 16) & 1u)) >> 16;
  return (unsigned short)r;
}
// packed fp32->bf16 (RNE, same rounding as f2b); gfx950 has the instruction but no builtin (T12/m240)
__device__ __forceinline__ uint32_t cvtpk(float a, float b){
  uint32_t d;
  asm volatile("v_cvt_pk_bf16_f32 %0, %1, %2" : "=v"(d) : "v"(a), "v"(b));
  return d;
}
__device__ __forceinline__ float selu_f(float x){
  const float lam = 1.0507009873554805f, alp = 1.6732632423543772f;
  return x > 0.f ? lam * x : lam * alp * (__expf(x) - 1.f);
}

// direct-to-LDS 16B DMA (compiler never auto-emits this; bypasses VGPR round-trip AND regalloc load-sinking)
__device__ __forceinline__ void gload_lds16(const void* g, void* l){
  __builtin_amdgcn_global_load_lds((const __attribute__((address_space(1))) void*)g,
                                   (__attribute__((address_space(3))) void*)l, 16, 0, 0);
}

// ---------------- W1+W2 swizzle in ONE dispatch: [K][256] f32 -> [K/32][256][32] bf16 ----------------
__global__ __launch_bounds__(256) void swizzleW2(const float* __restrict__ W1, const float* __restrict__ W2,
                                                 unsigned short* __restrict__ Wsw1, unsigned short* __restrict__ Wsw2){
  int i = blockIdx.x * 256 + threadIdx.x;          // grid covers FF*HH + HH*HH = 262144 exactly
  if (i < FF * HH){
    int k = i / HH, n = i % HH;
    Wsw1[(size_t)(k >> 5) * 8192 + n * 32 + (k & 31)] = f2b(W1[i]);
  } else {
    int i2 = i - FF * HH;
    int k = i2 / HH, n = i2 % HH;
    Wsw2[(size_t)(k >> 5) * 8192 + n * 32 + (k & 31)] = f2b(W2[i2]);
  }
}

// ---------------- CSR build ----------------
__global__ __launch_bounds__(256) void zero_deg(int* deg){
  int i = blockIdx.x * 256 + threadIdx.x;
  if (i < NN) deg[i] = 0;
}

__global__ __launch_bounds__(256) void deg_kernel(const int* __restrict__ dstA, int* __restrict__ deg){
  int i = blockIdx.x * 256 + threadIdx.x;
  if (i < ETOT){
    int d = (i < EE) ? dstA[i] : (i - EE);   // self-loops appended
    atomicAdd(&deg[d], 1);
  }
}

__global__ __launch_bounds__(256) void scanA(const int* __restrict__ deg, int* __restrict__ bsum){
  __shared__ int red[256];
  int c = blockIdx.x, tid = threadIdx.x;
  int base = c * 1024 + tid * 4;
  int s = 0;
#pragma unroll
  for (int j = 0; j < 4; j++){ int idx = base + j; if (idx < NN) s += deg[idx]; }
  red[tid] = s; __syncthreads();
  for (int off = 128; off > 0; off >>= 1){
    if (tid < off) red[tid] += red[tid + off];
    __syncthreads();
  }
  if (tid == 0) bsum[c] = red[0];
}

// scanB folded in: chunk base computed by an in-block reduce of bsum[0..c)
__global__ __launch_bounds__(256) void scanC(const int* __restrict__ deg, const int* __restrict__ bsum,
                                             int* __restrict__ row_ptr, int* __restrict__ fill_ptr){
  __shared__ int ts[256];
  __shared__ int cbase;
  int c = blockIdx.x, tid = threadIdx.x;
  int pb = (tid < c) ? bsum[tid] : 0;    // NCHUNK=49 <= 256
  ts[tid] = pb; __syncthreads();
  for (int off = 128; off > 0; off >>= 1){
    if (tid < off) ts[tid] += ts[tid + off];
    __syncthreads();
  }
  if (tid == 0) cbase = ts[0];
  __syncthreads();
  int base = c * 1024 + tid * 4;
  int v[4]; int s = 0;
#pragma unroll
  for (int j = 0; j < 4; j++){ int idx = base + j; v[j] = (idx < NN) ? deg[idx] : 0; s += v[j]; }
  ts[tid] = s; __syncthreads();
  for (int off = 1; off < 256; off <<= 1){
    int add = (tid >= off) ? ts[tid - off] : 0;
    __syncthreads();
    ts[tid] += add;
    __syncthreads();
  }
  int run = ts[tid] - s + cbase;
#pragma unroll
  for (int j = 0; j < 4; j++){
    int idx = base + j;
    if (idx < NN){ row_ptr[idx] = run; fill_ptr[idx] = run; }
    run += v[j];
  }
  if (c == 0 && tid == 0) row_ptr[NN] = ETOT;
}

__global__ __launch_bounds__(256) void fill_kernel(const int* __restrict__ srcA, const int* __restrict__ dstA,
                                                   int* __restrict__ fill_ptr, int* __restrict__ csr_src){
  int i = blockIdx.x * 256 + threadIdx.x;
  if (i < ETOT){
    int s = (i < EE) ? srcA[i] : (i - EE);
    int d = (i < EE) ? dstA[i] : (i - EE);
    int pos = atomicAdd(&fill_ptr[d], 1);
    csr_src[pos] = s;
  }
}

// ---------------- GEMM layer 1: fp32 A staged directly via DMA, 2 half-K phases, cvt_pk on read ----------------
// Kills the xbf pre-pass (saves 230 MB of convert traffic + a dispatch). LDS holds one 32x384 fp32
// half-panel (48 KB, 3 blk/CU); phases: stage(0),prefB,bar,compute(0),bar,stage(1),prefB,bar,compute(1).
// LDS->reg read converts 8 f32 -> bf16x8 with 4 v_cvt_pk_bf16_f32 (RNE == f2b, bitwise-identical output).
// Source-chunk XOR swizzle ch^(row&7) (rows are 1536B = bank-aligned); read side applies same involution
// per 16B chunk (pair addresses computed independently -> order-safe under odd masks).
__global__ __launch_bounds__(256, 3) void gemm1_f32(const float* __restrict__ A,
                                                 const unsigned short* __restrict__ Wsw,
                                                 const float* __restrict__ a_s, const float* __restrict__ a_d,
                                                 unsigned short* __restrict__ out,
                                                 float* __restrict__ als, float* __restrict__ ald, int M){
  __shared__ float Alf[32 * 384];                  // 48 KB
  const int tid = threadIdx.x;
  const int m0 = blockIdx.x * 32;
  const int lane = tid & 63, w = tid >> 6;
  const int koff = (lane >> 4) * 8;
  const int arow = lane & 15;
  const int nrow = w * 64 + (lane & 15);

  f32x4 acc[2][4];
#pragma unroll
  for (int rt = 0; rt < 2; rt++)
#pragma unroll
    for (int ct = 0; ct < 4; ct++) acc[rt][ct] = (f32x4){0.f, 0.f, 0.f, 0.f};

  const unsigned short* bbase = Wsw + ((size_t)nrow * 32 + koff);
  bf16x8 bcur[2][4];

  auto stage_half = [&](int p){
#pragma unroll
    for (int j = 0; j < 12; j++){
      int L16 = j * 256 + tid;                     // linear 16B(f32x4)-chunk index in half-panel
      int row = L16 / 96;
      int ch  = L16 - row * 96;
      int sch = ch ^ (row & 7);                    // inverse-swizzle the SOURCE (involution, stays in [0,96))
      int gr  = m0 + row; if (gr >= M) gr = M - 1; // clamp: garbage rows never stored
      gload_lds16(A + (size_t)gr * FF + p * 384 + sch * 4,
                  Alf + (size_t)(j * 256 + w * 64) * 4);   // wave-uniform dest; HW adds lane*16B
    }
  };

#pragma unroll
  for (int p = 0; p < 2; p++){
    if (p == 1) __syncthreads();                   // all phase-0 reads done before overwrite
    stage_half(p);
    // prefetch B slabs for first ks of this phase (overlaps DMA drain)
#pragma unroll
    for (int k2 = 0; k2 < 2; k2++)
#pragma unroll
      for (int ct = 0; ct < 4; ct++)
        bcur[k2][ct] = *(const bf16x8*)(bbase + (size_t)(p * 12 + k2) * 8192 + ct * 512);
    __syncthreads();                               // DMA visible

    for (int ks = 0; ks < 6; ks++){
      bf16x8 bnext[2][4];
      if (ks + 1 < 6){
#pragma unroll
        for (int k2 = 0; k2 < 2; k2++)
#pragma unroll
          for (int ct = 0; ct < 4; ct++)
            bnext[k2][ct] = *(const bf16x8*)(bbase + (size_t)(p * 12 + (ks + 1) * 2 + k2) * 8192 + ct * 512);
      }
      bf16x8 af[2][2];
#pragma unroll
      for (int k2 = 0; k2 < 2; k2++)
#pragma unroll
        for (int rt = 0; rt < 2; rt++){
          int R = rt * 16 + arow;
          int c = ks * 16 + k2 * 8 + (lane >> 4) * 2;          // even chunk index of 8-f32 fragment
          int m = R & 7;
          float4 v0 = *(const float4*)&Alf[R * 384 + ((c)     ^ m) * 4];
          float4 v1 = *(const float4*)&Alf[R * 384 + ((c + 1) ^ m) * 4];
          union { bf16x8 v; uint32_t u[4]; } X;
          X.u[0] = cvtpk(v0.x, v0.y); X.u[1] = cvtpk(v0.z, v0.w);
          X.u[2] = cvtpk(v1.x, v1.y); X.u[3] = cvtpk(v1.z, v1.w);
          af[k2][rt] = X.v;
        }
#pragma unroll
      for (int k2 = 0; k2 < 2; k2++)
#pragma unroll
        for (int rt = 0; rt < 2; rt++)
#pragma unroll
          for (int ct = 0; ct < 4; ct++)
            acc[rt][ct] = __builtin_amdgcn_mfma_f32_16x16x32_bf16(af[k2][rt], bcur[k2][ct], acc[rt][ct], 0, 0, 0);
      if (ks + 1 < 6){
#pragma unroll
        for (int k2 = 0; k2 < 2; k2++)
#pragma unroll
          for (int ct = 0; ct < 4; ct++) bcur[k2][ct] = bnext[k2][ct];
      }
    }
  }

  // ---- C write (bf16 h) ----
#pragma unroll
  for (int rt = 0; rt < 2; rt++){
    int mbase = m0 + rt * 16 + (lane >> 4) * 4;
#pragma unroll
    for (int r = 0; r < 4; r++){
      int m = mbase + r;
      if (m < M){
        size_t ro = (size_t)m * HH + w * 64 + (lane & 15);
        out[ro + 0]  = f2b(acc[rt][0][r]);
        out[ro + 16] = f2b(acc[rt][1][r]);
        out[ro + 32] = f2b(acc[rt][2][r]);
        out[ro + 48] = f2b(acc[rt][3][r]);
      }
    }
  }

  // ---- fused als/ald from fp32 accumulators ----
  float as_c[4], ad_c[4];
#pragma unroll
  for (int ct = 0; ct < 4; ct++){
    int col = w * 64 + ct * 16 + (lane & 15);
    as_c[ct] = a_s[col]; ad_c[ct] = a_d[col];
  }
  float ps[2][4], pd[2][4];
#pragma unroll
  for (int rt = 0; rt < 2; rt++)
#pragma unroll
    for (int r = 0; r < 4; r++){
      float s = 0.f, d = 0.f;
#pragma unroll
      for (int ct = 0; ct < 4; ct++){ float v = acc[rt][ct][r]; s += v * as_c[ct]; d += v * ad_c[ct]; }
      ps[rt][r] = s; pd[rt][r] = d;
    }
#pragma unroll
  for (int off = 1; off < 16; off <<= 1){
#pragma unroll
    for (int rt = 0; rt < 2; rt++)
#pragma unroll
      for (int r = 0; r < 4; r++){
        ps[rt][r] += __shfl_xor(ps[rt][r], off);
        pd[rt][r] += __shfl_xor(pd[rt][r], off);
      }
  }
  __syncthreads();
  float* red = Alf;
  if ((lane & 15) == 0){
    int q = lane >> 4;
#pragma unroll
    for (int rt = 0; rt < 2; rt++)
#pragma unroll
      for (int r = 0; r < 4; r++){
        int row = rt * 16 + q * 4 + r;
        red[w * 32 + row]       = ps[rt][r];
        red[128 + w * 32 + row] = pd[rt][r];
      }
  }
  __syncthreads();
  if (tid < 32){
    float s = red[tid] + red[32 + tid] + red[64 + tid] + red[96 + tid];
    float d = red[128 + tid] + red[160 + tid] + red[192 + tid] + red[224 + tid];
    int m = m0 + tid;
    if (m < M){ als[m] = s; ald[m] = d; }
  }
}

// ---------------- GEMM layer 2 (bf16 A, frozen v6 structure) ----------------
template<int K, int MINW>
__global__ __launch_bounds__(256, MINW) void gemm_mfma(const unsigned short* __restrict__ A,
                                                 const unsigned short* __restrict__ Wsw,
                                                 const float* __restrict__ a_s, const float* __restrict__ a_d,
                                                 unsigned short* __restrict__ out,
                                                 float* __restrict__ als, float* __restrict__ ald, int M){
  constexpr int CHROW = K / 8;
  __shared__ unsigned short Al[32 * K];
  const int tid = threadIdx.x;
  const int m0 = blockIdx.x * 32;
  const int lane = tid & 63, w = tid >> 6;
  const int koff = (lane >> 4) * 8;
  const int arow = lane & 15;
  const int nrow = w * 64 + (lane & 15);

  f32x4 acc[2][4];
#pragma unroll
  for (int rt = 0; rt < 2; rt++)
#pragma unroll
    for (int ct = 0; ct < 4; ct++) acc[rt][ct] = (f32x4){0.f, 0.f, 0.f, 0.f};

  constexpr int ROUNDS = (32 * CHROW) / 256;
#pragma unroll
  for (int j = 0; j < ROUNDS; j++){
    int L16 = j * 256 + tid;
    int row = L16 / CHROW;
    int ch  = L16 - row * CHROW;
    int sch = ch ^ (row & 7);
    int gr  = m0 + row; if (gr >= M) gr = M - 1;
    gload_lds16(A + (size_t)gr * K + sch * 8,
                &Al[(size_t)(j * 256 + w * 64) * 8]);
  }

  const unsigned short* bbase = Wsw + ((size_t)nrow * 32 + koff);
  bf16x8 bcur[2][4];
#pragma unroll
  for (int k2 = 0; k2 < 2; k2++)
#pragma unroll
    for (int ct = 0; ct < 4; ct++)
      bcur[k2][ct] = *(const bf16x8*)(bbase + (size_t)k2 * 8192 + ct * 512);

  __syncthreads();

  constexpr int NIT = K / 64;
  for (int ks = 0; ks < NIT; ks++){
    bf16x8 bnext[2][4];
    if (ks + 1 < NIT){
#pragma unroll
      for (int k2 = 0; k2 < 2; k2++)
#pragma unroll
        for (int ct = 0; ct < 4; ct++)
          bnext[k2][ct] = *(const bf16x8*)(bbase + (size_t)((ks + 1) * 2 + k2) * 8192 + ct * 512);
    }
    bf16x8 af[2][2];
#pragma unroll
    for (int k2 = 0; k2 < 2; k2++)
#pragma unroll
      for (int rt = 0; rt < 2; rt++){
        int R = rt * 16 + arow;
        int chb = (ks * 8 + k2 * 4 + (lane >> 4)) ^ (R & 7);
        af[k2][rt] = *(const bf16x8*)&Al[(size_t)R * K + chb * 8];
      }
#pragma unroll
    for (int k2 = 0; k2 < 2; k2++)
#pragma unroll
      for (int rt = 0; rt < 2; rt++)
#pragma unroll
        for (int ct = 0; ct < 4; ct++)
          acc[rt][ct] = __builtin_amdgcn_mfma_f32_16x16x32_bf16(af[k2][rt], bcur[k2][ct], acc[rt][ct], 0, 0, 0);
    if (ks + 1 < NIT){
#pragma unroll
      for (int k2 = 0; k2 < 2; k2++)
#pragma unroll
        for (int ct = 0; ct < 4; ct++) bcur[k2][ct] = bnext[k2][ct];
    }
  }

#pragma unroll
  for (int rt = 0; rt < 2; rt++){
    int mbase = m0 + rt * 16 + (lane >> 4) * 4;
#pragma unroll
    for (int r = 0; r < 4; r++){
      int m = mbase + r;
      if (m < M){
        size_t ro = (size_t)m * HH + w * 64 + (lane & 15);
        out[ro + 0]  = f2b(acc[rt][0][r]);
        out[ro + 16] = f2b(acc[rt][1][r]);
        out[ro + 32] = f2b(acc[rt][2][r]);
        out[ro + 48] = f2b(acc[rt][3][r]);
      }
    }
  }

  float as_c[4], ad_c[4];
#pragma unroll
  for (int ct = 0; ct < 4; ct++){
    int col = w * 64 + ct * 16 + (lane & 15);
    as_c[ct] = a_s[col]; ad_c[ct] = a_d[col];
  }
  float ps[2][4], pd[2][4];
#pragma unroll
  for (int rt = 0; rt < 2; rt++)
#pragma unroll
    for (int r = 0; r < 4; r++){
      float s = 0.f, d = 0.f;
#pragma unroll
      for (int ct = 0; ct < 4; ct++){ float v = acc[rt][ct][r]; s += v * as_c[ct]; d += v * ad_c[ct]; }
      ps[rt][r] = s; pd[rt][r] = d;
    }
#pragma unroll
  for (int off = 1; off < 16; off <<= 1){
#pragma unroll
    for (int rt = 0; rt < 2; rt++)
#pragma unroll
      for (int r = 0; r < 4; r++){
        ps[rt][r] += __shfl_xor(ps[rt][r], off);
        pd[rt][r] += __shfl_xor(pd[rt][r], off);
      }
  }
  __syncthreads();
  float* red = (float*)Al;
  if ((lane & 15) == 0){
    int q = lane >> 4;
#pragma unroll
    for (int rt = 0; rt < 2; rt++)
#pragma unroll
      for (int r = 0; r < 4; r++){
        int row = rt * 16 + q * 4 + r;
        red[w * 32 + row]       = ps[rt][r];
        red[128 + w * 32 + row] = pd[rt][r];
      }
  }
  __syncthreads();
  if (tid < 32){
    float s = red[tid] + red[32 + tid] + red[64 + tid] + red[96 + tid];
    float d = red[128 + tid] + red[160 + tid] + red[192 + tid] + red[224 + tid];
    int m = m0 + tid;
    if (m < M){ als[m] = s; ald[m] = d; }
  }
}

// ---------------- agg v4: softmax + aggregate; 8 edges/step, 4 gather-loads in flight ----------------
// v2 consumed the pair it had just issued (full L3 latency exposed per 4 edges). v4 issues 4 independent
// row loads per 8-edge step before any consume; s_waitcnt drains progressively (vmcnt 3..0).
__global__ __launch_bounds__(256) void agg_wave(const unsigned short* __restrict__ h,
    const float* __restrict__ als, const float* __restrict__ ald,
    const int* __restrict__ row_ptr, const int* __restrict__ csr_src,
    const float* __restrict__ bias, unsigned short* __restrict__ outp){
  int node = blockIdx.x * 4 + (threadIdx.x >> 6);
  int lane = threadIdx.x & 63;
  if (node >= NN) return;
  int base = row_ptr[node];
  int deg  = row_ptr[node + 1] - base;
  float aldd = ald[node];
  float den = 0.f;
  float a[8] = {0.f, 0.f, 0.f, 0.f, 0.f, 0.f, 0.f, 0.f};
  const int f8 = (lane & 31) * 8;        // this lane's 8-feature slice
  const int half = lane >> 5;            // 0: even edges, 1: odd edges
  for (int p0 = 0; p0 < deg; p0 += 64){
    int cnt = min(64, deg - p0);         // wave-uniform
    float ev = 0.f; int s = 0;
    if (lane < cnt){
      s = csr_src[base + p0 + lane];
      float v = als[s] + aldd;
      v = v > 0.f ? v : 0.2f * v;        // leaky_relu(0.2)
      ev = __expf(v);
    }
    den += ev;
    int j = 0;
    for (; j + 8 <= cnt; j += 8){        // 8 edges/step, 4 loads issued before consume
      int j0 = j + half, j1 = j + 2 + half, j2 = j + 4 + half, j3 = j + 6 + half;
      int s0 = __shfl(s, j0), s1 = __shfl(s, j1), s2 = __shfl(s, j2), s3 = __shfl(s, j3);
      float e0 = __shfl(ev, j0), e1 = __shfl(ev, j1), e2 = __shfl(ev, j2), e3 = __shfl(ev, j3);
      us8 g0 = *(const us8*)&h[(size_t)s0 * HH + f8];
      us8 g1 = *(const us8*)&h[(size_t)s1 * HH + f8];
      us8 g2 = *(const us8*)&h[(size_t)s2 * HH + f8];
      us8 g3 = *(const us8*)&h[(size_t)s3 * HH + f8];
#pragma unroll
      for (int i = 0; i < 8; i++) a[i] += e0 * b2f(g0[i]) + e1 * b2f(g1[i]);
#pragma unroll
      for (int i = 0; i < 8; i++) a[i] += e2 * b2f(g2[i]) + e3 * b2f(g3[i]);
    }
    for (; j + 4 <= cnt; j += 4){        // 4-edge step
      int j0 = j + half, j1 = j + 2 + half;
      int s0 = __shfl(s, j0), s1 = __shfl(s, j1);
      float e0 = __shfl(ev, j0), e1 = __shfl(ev, j1);
      us8 g0 = *(const us8*)&h[(size_t)s0 * HH + f8];
      us8 g1 = *(const us8*)&h[(size_t)s1 * HH + f8];
#pragma unroll
      for (int i = 0; i < 8; i++) a[i] += e0 * b2f(g0[i]) + e1 * b2f(g1[i]);
    }
    for (; j < cnt; j += 2){             // 0-3 remaining edges
      int jj = j + half;
      int sj = __shfl(s, jj & 63);       // lanes >= cnt hold s=0 -> safe address
      float ejr = __shfl(ev, jj & 63);
      float ej = (jj < cnt) ? ejr : 0.f;
      us8 gj = *(const us8*)&h[(size_t)sj * HH + f8];
#pragma unroll
      for (int i = 0; i < 8; i++) a[i] += ej * b2f(gj[i]);
    }
  }
  for (int off = 32; off > 0; off >>= 1) den += __shfl_xor(den, off);
#pragma unroll
  for (int i = 0; i < 8; i++) a[i] += __shfl_xor(a[i], 32);   // merge even/odd halves
  if (lane < 32){
    float inv = 1.f / den;
    float4 b4a = *(const float4*)&bias[f8];
    float4 b4b = *(const float4*)&bias[f8 + 4];
    us8 o;
    o[0] = f2b(selu_f(a[0] * inv + b4a.x));
    o[1] = f2b(selu_f(a[1] * inv + b4a.y));
    o[2] = f2b(selu_f(a[2] * inv + b4a.z));
    o[3] = f2b(selu_f(a[3] * inv + b4a.w));
    o[4] = f2b(selu_f(a[4] * inv + b4b.x));
    o[5] = f2b(selu_f(a[5] * inv + b4b.y));
    o[6] = f2b(selu_f(a[6] * inv + b4b.z));
    o[7] = f2b(selu_f(a[7] * inv + b4b.w));
    *(us8*)&outp[(size_t)node * HH + f8] = o;
  }
}

// ---------------- fused head: pool + z1 + news + final per graph (binary-searched bounds) ----------------
__global__ __launch_bounds__(256) void head_kernel(const unsigned short* __restrict__ x3,
    const int* __restrict__ batch, const float* __restrict__ x,
    const float* __restrict__ W0, const float* __restrict__ b0,
    const float* __restrict__ Wf1, const float* __restrict__ bf1,
    const float* __restrict__ Wf2, const float* __restrict__ bf2,
    float* __restrict__ out){
  __shared__ float pr[HH];      // pooled (selu applied)
  __shared__ float xr[FF];      // root-node features
  __shared__ float zc[HH];      // concat [z1, news]
  __shared__ int se[2];
  __shared__ float l0s[2], l1s[2];
  int g = blockIdx.x, t = threadIdx.x;
  if (t < 2){                   // graph bounds: first n with batch[n] >= g (+t)
    int target = g + t, lo = 0, hi = NN;
    while (lo < hi){ int mid = (lo + hi) >> 1; if (batch[mid] < target) lo = mid + 1; else hi = mid; }
    se[t] = lo;
  }
  __syncthreads();
  int s = se[0], e = se[1];
  {                             // global mean pool over the graph, feature t
    float acc = 0.f;
    for (int n = s; n < e; n++) acc += b2f(x3[(size_t)n * HH + t]);
    pr[t] = selu_f(acc / (float)(e - s));
  }
  for (int k = t; k < FF; k += 256) xr[k] = x[(size_t)s * FF + k];   // root = first node
  __syncthreads();
  if (t < NHIDD){               // waves 0-1: z1 = selu(pr @ Wf1 + bf1)
    float acc = 0.f;
    for (int k = 0; k < HH; k++) acc += pr[k] * Wf1[k * NHIDD + t];
    zc[t] = selu_f(acc + bf1[t]);
  } else {                      // waves 2-3: news = relu(x_root @ W0 + b0)
    int t2 = t - NHIDD;
    float acc = 0.f;
    for (int k = 0; k < FF; k++) acc += xr[k] * W0[k * NHIDD + t2];
    acc += b0[t2];
    zc[NHIDD + t2] = acc > 0.f ? acc : 0.f;
  }
  __syncthreads();
  if (t < NHIDD){               // z2 = relu(zc @ Wf1 + bf1); logits; 2-wave reduce
    float acc = 0.f;
    for (int k = 0; k < HH; k++) acc += zc[k] * Wf1[k * NHIDD + t];
    float z2 = acc + bf1[t]; z2 = z2 > 0.f ? z2 : 0.f;
    float p0 = z2 * Wf2[t * CC + 0];
    float p1 = z2 * Wf2[t * CC + 1];
    for (int off = 32; off > 0; off >>= 1){ p0 += __shfl_xor(p0, off); p1 += __shfl_xor(p1, off); }
    if ((t & 63) == 0){ l0s[t >> 6] = p0; l1s[t >> 6] = p1; }
  }
  __syncthreads();
  if (t == 0){
    float l0 = l0s[0] + l0s[1] + bf2[0];
    float l1 = l1s[0] + l1s[1] + bf2[1];
    float mx = fmaxf(l0, l1);
    float lse = mx + logf(__expf(l0 - mx) + __expf(l1 - mx));
    out[g * CC + 0] = l0 - lse;
    out[g * CC + 1] = l1 - lse;
  }
}

extern "C" void kernel_launch(void* const* d_in, const int* in_sizes, int n_in,
                              void* d_out, int out_size, void* d_ws, size_t ws_size,
                              hipStream_t stream){
  const float* x          = (const float*)d_in[0];
  const int* edge_index   = (const int*)d_in[1];
  const int* batch        = (const int*)d_in[2];
  const float* W1  = (const float*)d_in[3];
  const float* as1 = (const float*)d_in[4];
  const float* ad1 = (const float*)d_in[5];
  const float* b1  = (const float*)d_in[6];
  const float* W2  = (const float*)d_in[7];
  const float* as2 = (const float*)d_in[8];
  const float* ad2 = (const float*)d_in[9];
  const float* b2  = (const float*)d_in[10];
  const float* W0  = (const float*)d_in[11];
  const float* b0  = (const float*)d_in[12];
  const float* Wf1 = (const float*)d_in[13];
  const float* bf1 = (const float*)d_in[14];
  const float* Wf2 = (const float*)d_in[15];
  const float* bf2 = (const float*)d_in[16];
  float* out = (float*)d_out;

  char* w = (char*)d_ws;
  size_t off = 0;
  auto alloc = [&](size_t bytes){ size_t o = off; off += (bytes + 255) & ~(size_t)255; return o; };
  unsigned short* h    = (unsigned short*)(w + alloc((size_t)NN * HH * 2));   // 25.6 MB
  unsigned short* x2   = (unsigned short*)(w + alloc((size_t)NN * HH * 2));   // 25.6 MB
  unsigned short* Wsw1 = (unsigned short*)(w + alloc((size_t)FF * HH * 2));
  unsigned short* Wsw2 = (unsigned short*)(w + alloc((size_t)HH * HH * 2));
  float* als     = (float*)(w + alloc((size_t)NN * 4));
  float* ald     = (float*)(w + alloc((size_t)NN * 4));
  int*   deg     = (int*)(w + alloc((size_t)NN * 4));
  int*   row_ptr = (int*)(w + alloc((size_t)(NN + 1) * 4));
  int*   fillp   = (int*)(w + alloc((size_t)NN * 4));
  int*   csr_src = (int*)(w + alloc((size_t)ETOT * 4));
  int*   bsum    = (int*)(w + alloc(64 * 4));

  const int* srcA = edge_index;
  const int* dstA = edge_index + EE;

  // weight swizzle (both layers, one dispatch)
  swizzleW2<<<(FF * HH + HH * HH) / 256, 256, 0, stream>>>(W1, W2, Wsw1, Wsw2);

  // CSR build (shared by both GAT layers)
  zero_deg<<<(NN + 255) / 256, 256, 0, stream>>>(deg);
  deg_kernel<<<(ETOT + 255) / 256, 256, 0, stream>>>(dstA, deg);
  scanA<<<NCHUNK, 256, 0, stream>>>(deg, bsum);
  scanC<<<NCHUNK, 256, 0, stream>>>(deg, bsum, row_ptr, fillp);
  fill_kernel<<<(ETOT + 255) / 256, 256, 0, stream>>>(srcA, dstA, fillp, csr_src);

  const int gemm_grid = (NN + 31) / 32;   // 32-row full-K panels -> 1563 blocks
  // GAT layer 1 (A = fp32 x via DMA, cvt on LDS read; als/ald fused)
  gemm1_f32<<<gemm_grid, 256, 0, stream>>>(x, Wsw1, as1, ad1, h, als, ald, NN);
  agg_wave<<<(NN + 3) / 4, 256, 0, stream>>>(h, als, ald, row_ptr, csr_src, b1, x2);
  // GAT layer 2 (A = bf16 x2)
  gemm_mfma<HH, 3><<<gemm_grid, 256, 0, stream>>>(x2, Wsw2, as2, ad2, h, als, ald, NN);
  agg_wave<<<(NN + 3) / 4, 256, 0, stream>>>(h, als, ald, row_ptr, csr_src, b2, x2);
  // fused head (pool + z1 + news + final; bounds via binary search)
  head_kernel<<<GG, 256, 0, stream>>>(x2, batch, x, W0, b0, Wf1, bf1, Wf2, bf2, out);
}